// Round 2
// baseline (306.375 us; speedup 1.0000x reference)
//
#include <hip/hip_runtime.h>
#include <stdint.h>

// Problem geometry: t is (8, 3, 1024, 1024) fp32.
#define W_IMG 1024
#define H_IMG 1024
#define N_ELEM 25165824u            // 8*3*1024*1024

// JAX threefry2x32, key = (0, 42) [jax.random.key(42)], partitionable mode:
// counter = (hi=0, lo=i); 32-bit output = out0 ^ out1 (xor-fold).
// ks = [0, 42, 0^42^0x1BD11BDA = 0x1BD11BF0]
__device__ __forceinline__ uint32_t threefry_xor_0_42(uint32_t ctr_lo) {
    const uint32_t k1 = 42u;
    const uint32_t k2 = 0x1BD11BF0u;
    uint32_t x0 = 0u;              // counts_hi = 0, + ks[0] = 0
    uint32_t x1 = ctr_lo + k1;     // counts_lo + ks[1]
#define TF_ROUND(r) { x0 += x1; x1 = (x1 << (r)) | (x1 >> (32 - (r))); x1 ^= x0; }
    // 5 groups of 4 rounds; subkey injection after each group (s = 1..5)
    TF_ROUND(13) TF_ROUND(15) TF_ROUND(26) TF_ROUND(6)
    x0 += k1;  x1 += k2 + 1u;
    TF_ROUND(17) TF_ROUND(29) TF_ROUND(16) TF_ROUND(24)
    x0 += k2;  x1 += 2u;           // ks[0]=0
    TF_ROUND(13) TF_ROUND(15) TF_ROUND(26) TF_ROUND(6)
    /* x0 += 0 */ x1 += k1 + 3u;
    TF_ROUND(17) TF_ROUND(29) TF_ROUND(16) TF_ROUND(24)
    x0 += k1;  x1 += k2 + 4u;
    TF_ROUND(13) TF_ROUND(15) TF_ROUND(26) TF_ROUND(6)
    x0 += k2;  x1 += 5u;
#undef TF_ROUND
    return x0 ^ x1;
}

// jax uniform [0,1): bitcast((bits >> 9) | 0x3f800000) - 1.0
__device__ __forceinline__ float bits_to_uniform(uint32_t b) {
    return __uint_as_float((b >> 9) | 0x3f800000u) - 1.0f;
}

__global__ __launch_bounds__(256) void neighbor_noiser_kernel(
        const float* __restrict__ t, float* __restrict__ out, unsigned n) {
    unsigned j = blockIdx.x * 256u + threadIdx.x;
    if (j >= n) return;

    unsigned x = j & (W_IMG - 1);
    unsigned y = (j >> 10) & (H_IMG - 1);

    // replicate-padded neighbor flat indices (shifts act only on H,W)
    unsigned up = (y == 0)          ? j : j - W_IMG;
    unsigned dn = (y == H_IMG - 1)  ? j : j + W_IMG;
    unsigned lf = (x == 0)          ? j : j - 1;
    unsigned rt = (x == W_IMG - 1)  ? j : j + 1;

    float up_t = t[up];
    float dn_t = t[dn];
    float lf_t = t[lf];
    float rt_t = t[rt];

    // r flat layout: (4, 8,3,1024,1024); element (d, j) at flat index d*N + j.
    // partitionable threefry: r.flat[i] from counter (0, i), xor-folded.
    uint32_t b_up = threefry_xor_0_42(j);
    uint32_t b_dn = threefry_xor_0_42(j + N_ELEM);
    uint32_t b_lf = threefry_xor_0_42(j + 2u * N_ELEM);
    uint32_t b_rt = threefry_xor_0_42(j + 3u * N_ELEM);

    float up_r = bits_to_uniform(b_up);
    float dn_r = bits_to_uniform(b_dn);
    float lf_r = bits_to_uniform(b_lf);
    float rt_r = bits_to_uniform(b_rt);

    float num = up_t * up_r + dn_t * dn_r + lf_t * lf_r + rt_t * rt_r;
    float den = (up_r + dn_r) + (lf_r + rt_r);

    out[j] = __fdividef(num, den);
}

extern "C" void kernel_launch(void* const* d_in, const int* in_sizes, int n_in,
                              void* d_out, int out_size, void* d_ws, size_t ws_size,
                              hipStream_t stream) {
    const float* t = (const float*)d_in[0];
    float* out = (float*)d_out;
    unsigned n = (unsigned)out_size;          // 25165824
    unsigned block = 256;
    unsigned grid = (n + block - 1) / block;  // 98304 blocks
    neighbor_noiser_kernel<<<dim3(grid), dim3(block), 0, stream>>>(t, out, n);
}

// Round 3
// 302.807 us; speedup vs baseline: 1.0118x; 1.0118x over previous
//
#include <hip/hip_runtime.h>
#include <stdint.h>

// Problem geometry: t is (8, 3, 1024, 1024) fp32.
#define W_IMG 1024u
#define H_IMG 1024u
#define N_ELEM 25165824u            // 8*3*1024*1024

// rotl via single v_alignbit_b32: alignbit(x,x,32-r) = rotr(x,32-r) = rotl(x,r)
#define ROTL(x, r) __builtin_amdgcn_alignbit((x), (x), 32u - (r))

// JAX threefry2x32, key = (0, 42) [jax.random.key(42)], partitionable mode:
// counter = (hi=0, lo=i); 32-bit output = out0 ^ out1 (xor-fold).
// ks = [0, 42, 0^42^0x1BD11BDA = 0x1BD11BF0]
__device__ __forceinline__ uint32_t threefry_xor_0_42(uint32_t ctr_lo) {
    const uint32_t k1 = 42u;
    const uint32_t k2 = 0x1BD11BF0u;
    uint32_t x0 = 0u;              // counts_hi = 0, + ks[0] = 0
    uint32_t x1 = ctr_lo + k1;     // counts_lo + ks[1]
#define TF_ROUND(r) { x0 += x1; x1 = ROTL(x1, r); x1 ^= x0; }
    TF_ROUND(13u) TF_ROUND(15u) TF_ROUND(26u) TF_ROUND(6u)
    x0 += k1;  x1 += k2 + 1u;
    TF_ROUND(17u) TF_ROUND(29u) TF_ROUND(16u) TF_ROUND(24u)
    x0 += k2;  x1 += 2u;           // ks[0]=0
    TF_ROUND(13u) TF_ROUND(15u) TF_ROUND(26u) TF_ROUND(6u)
    /* x0 += 0 */ x1 += k1 + 3u;
    TF_ROUND(17u) TF_ROUND(29u) TF_ROUND(16u) TF_ROUND(24u)
    x0 += k1;  x1 += k2 + 4u;
    TF_ROUND(13u) TF_ROUND(15u) TF_ROUND(26u) TF_ROUND(6u)
    x0 += k2;  x1 += 5u;
#undef TF_ROUND
    return x0 ^ x1;
}

// jax uniform [0,1): bitcast((bits >> 9) | 0x3f800000) - 1.0
__device__ __forceinline__ float bits_to_uniform(uint32_t b) {
    return __uint_as_float((b >> 9) | 0x3f800000u) - 1.0f;
}

// 4 pixels per thread along x. 256-thread block = exactly one image row.
__global__ __launch_bounds__(256) void neighbor_noiser_kernel(
        const float* __restrict__ t, float* __restrict__ out) {
    unsigned tid = blockIdx.x * 256u + threadIdx.x;
    unsigned j0 = tid * 4u;                  // first pixel of this thread's quad

    unsigned x4 = j0 & (W_IMG - 1u);         // multiple of 4
    unsigned y  = (j0 >> 10) & (H_IMG - 1u);

    const float4* t4 = (const float4*)t;
    float4 c = t4[j0 >> 2];
    float4 u = t4[(y == 0u            ? j0 : j0 - W_IMG) >> 2];
    float4 d = t4[(y == H_IMG - 1u    ? j0 : j0 + W_IMG) >> 2];
    float lf0 = (x4 == 0u)            ? c.x : t[j0 - 1u];
    float rt3 = (x4 == W_IMG - 4u)    ? c.w : t[j0 + 4u];

    float uv[4] = {u.x, u.y, u.z, u.w};
    float dv[4] = {d.x, d.y, d.z, d.w};
    float lv[4] = {lf0, c.x, c.y, c.z};
    float rv[4] = {c.y, c.z, c.w, rt3};
    float o[4];

#pragma unroll
    for (int i = 0; i < 4; ++i) {
        unsigned j = j0 + (unsigned)i;
        // r flat layout (4, 8,3,1024,1024): element (dir, j) at dir*N + j.
        float up_r = bits_to_uniform(threefry_xor_0_42(j));
        float dn_r = bits_to_uniform(threefry_xor_0_42(j + N_ELEM));
        float lf_r = bits_to_uniform(threefry_xor_0_42(j + 2u * N_ELEM));
        float rt_r = bits_to_uniform(threefry_xor_0_42(j + 3u * N_ELEM));

        float num = uv[i] * up_r + dv[i] * dn_r + lv[i] * lf_r + rv[i] * rt_r;
        float den = (up_r + dn_r) + (lf_r + rt_r);
        o[i] = __fdividef(num, den);
    }

    ((float4*)out)[j0 >> 2] = make_float4(o[0], o[1], o[2], o[3]);
}

extern "C" void kernel_launch(void* const* d_in, const int* in_sizes, int n_in,
                              void* d_out, int out_size, void* d_ws, size_t ws_size,
                              hipStream_t stream) {
    const float* t = (const float*)d_in[0];
    float* out = (float*)d_out;
    // N = 25165824 elements, 4 per thread, 256 per block -> 24576 blocks exact.
    unsigned blocks = N_ELEM / (4u * 256u);
    neighbor_noiser_kernel<<<dim3(blocks), dim3(256), 0, stream>>>(t, out);
}

// Round 4
// 297.929 us; speedup vs baseline: 1.0283x; 1.0164x over previous
//
#include <hip/hip_runtime.h>
#include <stdint.h>

// Problem geometry: t is (8, 3, 1024, 1024) fp32.
#define W_IMG 1024u
#define H_IMG 1024u
#define N_ELEM 25165824u            // 8*3*1024*1024

// rotl via single v_alignbit_b32: alignbit(x,x,32-r) = rotl(x,r)
#define ROTL(x, r) __builtin_amdgcn_alignbit((x), (x), 32u - (r))

// JAX threefry2x32, key = (0, 42), partitionable mode:
// counter = (hi=0, lo=i); 32-bit output = out0 ^ out1 (xor-fold).
// ks = [0, 42, 0x1BD11BF0]. Takes x1_init = ctr + 42 (caller folds constants).
__device__ __forceinline__ uint32_t threefry_xor_from_x1(uint32_t x1) {
    const uint32_t k1 = 42u;
    const uint32_t k2 = 0x1BD11BF0u;
    uint32_t x0 = 0u;
#define TF_ROUND(r) { x0 += x1; x1 = ROTL(x1, r); x1 ^= x0; }
    TF_ROUND(13u) TF_ROUND(15u) TF_ROUND(26u) TF_ROUND(6u)
    x0 += k1;  x1 += k2 + 1u;
    TF_ROUND(17u) TF_ROUND(29u) TF_ROUND(16u) TF_ROUND(24u)
    x0 += k2;  x1 += 2u;
    TF_ROUND(13u) TF_ROUND(15u) TF_ROUND(26u) TF_ROUND(6u)
    x1 += k1 + 3u;
    TF_ROUND(17u) TF_ROUND(29u) TF_ROUND(16u) TF_ROUND(24u)
    x0 += k1;  x1 += k2 + 4u;
    TF_ROUND(13u) TF_ROUND(15u) TF_ROUND(26u) TF_ROUND(6u)
    x0 += k2;  x1 += 5u;
#undef TF_ROUND
    return x0 ^ x1;
}

// jax uniform in [1,2): bitcast((bits>>9)|0x3f800000). Single v_alignbit:
// alignbit(0x7F, b, 9) = (0x7F<<23) | (b>>9) = 0x3f800000 | (b>>9).
__device__ __forceinline__ float bits_to_1_2(uint32_t b) {
    return __uint_as_float(__builtin_amdgcn_alignbit(0x7Fu, b, 9u));
}

// One pixel's weighted blend. Weights w = f - 1 with f in [1,2):
// num = sum t_i*(f_i-1) = fma-chain; den = sum f_i - 4.
__device__ __forceinline__ float blend_pixel(
        unsigned j, float ut, float dt, float lt, float rt) {
    // counters: dir*N + j, with +42 key-add folded into the literal.
    float fu = bits_to_1_2(threefry_xor_from_x1(j + 42u));
    float fd = bits_to_1_2(threefry_xor_from_x1(j + (N_ELEM + 42u)));
    float fl = bits_to_1_2(threefry_xor_from_x1(j + (2u * N_ELEM + 42u)));
    float fr = bits_to_1_2(threefry_xor_from_x1(j + (3u * N_ELEM + 42u)));
    float wu = fu - 1.0f, wd = fd - 1.0f, wl = fl - 1.0f, wr = fr - 1.0f;
    float num = fmaf(ut, wu, fmaf(dt, wd, fmaf(lt, wl, rt * wr)));
    float den = (wu + wd) + (wl + wr);
    return __fdividef(num, den);
}

// 4 pixels per thread along x. 256-thread block = exactly one image row.
__global__ __launch_bounds__(256) void neighbor_noiser_kernel(
        const float* __restrict__ t, float* __restrict__ out) {
    unsigned tid = blockIdx.x * 256u + threadIdx.x;
    unsigned j0 = tid * 4u;                  // first pixel of this thread's quad

    unsigned x4 = j0 & (W_IMG - 1u);         // multiple of 4
    unsigned y  = (j0 >> 10) & (H_IMG - 1u);

    const float4* t4 = (const float4*)t;
    float4 c = t4[j0 >> 2];
    float4 u = t4[(y == 0u            ? j0 : j0 - W_IMG) >> 2];
    float4 d = t4[(y == H_IMG - 1u    ? j0 : j0 + W_IMG) >> 2];
    float lf0 = (x4 == 0u)            ? c.x : t[j0 - 1u];
    float rt3 = (x4 == W_IMG - 4u)    ? c.w : t[j0 + 4u];

    float4 o;
    o.x = blend_pixel(j0,      u.x, d.x, lf0, c.y);
    o.y = blend_pixel(j0 + 1u, u.y, d.y, c.x, c.z);
    o.z = blend_pixel(j0 + 2u, u.z, d.z, c.y, c.w);
    o.w = blend_pixel(j0 + 3u, u.w, d.w, c.z, rt3);

    ((float4*)out)[j0 >> 2] = o;
}

extern "C" void kernel_launch(void* const* d_in, const int* in_sizes, int n_in,
                              void* d_out, int out_size, void* d_ws, size_t ws_size,
                              hipStream_t stream) {
    const float* t = (const float*)d_in[0];
    float* out = (float*)d_out;
    // N = 25165824 elements, 4 per thread, 256 per block -> 24576 blocks exact.
    unsigned blocks = N_ELEM / (4u * 256u);
    neighbor_noiser_kernel<<<dim3(blocks), dim3(256), 0, stream>>>(t, out);
}